// Round 6
// baseline (1973.537 us; speedup 1.0000x reference)
//
#include <hip/hip_runtime.h>
#include <cmath>

#define B_   128
#define N_   196
#define ENC_ 2048
#define DEC_ 512
#define ATT_ 512
#define EMB_ 512
#define V_   10000
#define TS_  20     // T-1 decode steps
#define HCAT_ 12672 // 512 (W_w) + 2048 (Whh) + 10112 (fcn padded)
#define HOUT_ 2560  // [w_ah(512) | hg(2048)]
#define KSPLIT_ 8   // split-K for gates GEMM

typedef unsigned short u16;
typedef short s16x8 __attribute__((ext_vector_type(8)));   // 8 bf16 = 4 VGPRs (MFMA A/B frag)
typedef float f32x4 __attribute__((ext_vector_type(4)));   // MFMA C/D frag
typedef unsigned short u16x4 __attribute__((ext_vector_type(4)));
typedef unsigned short u16x2 __attribute__((ext_vector_type(2)));

// fast tanh: (e^{2x}-1)/(e^{2x}+1), clamp |x|<=8. ~6 VALU vs ~25 libm; err ~1e-7.
__device__ __forceinline__ float fast_tanh(float x) {
  float cx = fminf(fmaxf(x, -8.f), 8.f);
  float e = __expf(2.f * cx);
  return (e - 1.f) * __builtin_amdgcn_rcpf(e + 1.f);
}
__device__ __forceinline__ float fast_sigmoid(float x) {
  float cx = fminf(fmaxf(x, -30.f), 30.f);
  return __builtin_amdgcn_rcpf(1.f + __expf(-cx));
}

__device__ __forceinline__ u16 f2bf(float x) {  // round-to-nearest-even
  union { float f; unsigned u; } v; v.f = x;
  unsigned r = v.u + 0x7fff + ((v.u >> 16) & 1);
  return (u16)(r >> 16);
}
__device__ __forceinline__ float bf2f(u16 h) {
  union { float f; unsigned u; } v; v.u = ((unsigned)h) << 16; return v.f;
}

typedef const __attribute__((address_space(1))) void gas_t;
typedef __attribute__((address_space(3))) void las_t;
__device__ __forceinline__ void gld_lds16(const void* g, void* l) {
  __builtin_amdgcn_global_load_lds((gas_t*)g, (las_t*)l, 16, 0, 0);
}

// ---------------------------------------------------------------------------
// bf16 MFMA GEMM: C(M,N) = A(M,K) @ Bt(N,K)^T [+ bias]
// Tile 128x128, BK=64 (8 K-iters at K=512 -> half the barriers of BK=32),
// 256 threads (4 waves, 2x2), 16x16x32 MFMA, double-buffered LDS (64 KB).
// Epilogue routing: mode 1 -> atomicAdd C; mode 2 -> split-K partials
// (C += z*128*ldc, plain stores); Cb -> bf16 store; C2 (cols>=csplit) ->
// fp32 store with ldc2 (dual-output for the fused h-GEMM); else fp32 C.
__global__ __launch_bounds__(256, 2) void k_mfma(
    const u16* __restrict__ A, int lda,
    const u16* __restrict__ Bt, int ldb,
    const float* __restrict__ bias,
    float* __restrict__ C, u16* __restrict__ Cb, int ldc, int Nbound,
    float* __restrict__ C2, int csplit, int ldc2,
    int K, int mode) {
  __shared__ __align__(16) u16 As[2][128 * 64];
  __shared__ __align__(16) u16 Bs[2][128 * 64];

  const int tid = threadIdx.x;
  const int bm = blockIdx.y * 128;
  const int bn = blockIdx.x * 128;
  const int kchunk = K / gridDim.z;
  const int k0 = blockIdx.z * kchunk;
  const int kend = k0 + kchunk;
  if (mode == 2) C += (size_t)blockIdx.z * 128 * ldc;   // split-K partial buffer

  // staging: thread -> one 16B chunk; 4 passes/matrix (32 rows per pass)
  const int r0 = tid >> 3;          // row-within-pass 0..31
  const int kb = (tid & 7) * 8;     // k offset 0..56
  const u16* ga = A + (size_t)(bm + r0) * lda + kb;
  const u16* gb = Bt + (size_t)(bn + r0) * ldb + kb;

  const int w = tid >> 6;
  const int lane = tid & 63;
  const int wm = (w & 1) * 64;
  const int wn = (w >> 1) * 64;
  const int r16 = lane & 15;
  const int kq = lane >> 4;

  f32x4 acc[4][4] = {};

  auto STAGE = [&](int buf, int k) {
#pragma unroll
    for (int j = 0; j < 4; ++j) {
      gld_lds16(ga + (size_t)(j * 32) * lda + k, &As[buf][j * 2048 + tid * 8]);
      gld_lds16(gb + (size_t)(j * 32) * ldb + k, &Bs[buf][j * 2048 + tid * 8]);
    }
  };

  STAGE(0, k0);
  __syncthreads();               // drain prologue loads; buf0 ready
  int cur = 0;
  for (int k = k0; k < kend; k += 64) {
    if (k + 64 < kend) STAGE(cur ^ 1, k + 64);   // prefetch next tile
    s16x8 af[2][4], bfr[2][4];
#pragma unroll
    for (int s = 0; s < 2; ++s)
#pragma unroll
      for (int i = 0; i < 4; ++i) {
        af[s][i]  = *(const s16x8*)&As[cur][(wm + i * 16 + r16) * 64 + s * 32 + kq * 8];
        bfr[s][i] = *(const s16x8*)&Bs[cur][(wn + i * 16 + r16) * 64 + s * 32 + kq * 8];
      }
#pragma unroll
    for (int s = 0; s < 2; ++s)
#pragma unroll
      for (int mi = 0; mi < 4; ++mi)
#pragma unroll
        for (int ni = 0; ni < 4; ++ni)
          acc[mi][ni] = __builtin_amdgcn_mfma_f32_16x16x32_bf16(af[s][mi], bfr[s][ni], acc[mi][ni], 0, 0, 0);
    __syncthreads();             // publish prefetched buf + protect cur
    cur ^= 1;
  }

  // C/D layout: col = lane&15, row = quad*4 + reg (m89-verified)
#pragma unroll
  for (int ni = 0; ni < 4; ++ni) {
    int col = bn + wn + ni * 16 + r16;
    if (col < Nbound) {
      float bv = bias ? bias[col] : 0.f;
#pragma unroll
      for (int mi = 0; mi < 4; ++mi) {
#pragma unroll
        for (int r = 0; r < 4; ++r) {
          int row = bm + wm + mi * 16 + kq * 4 + r;
          float v = acc[mi][ni][r] + bv;
          if (mode == 1)                  atomicAdd(&C[(size_t)row * ldc + col], v);
          else if (Cb)                    Cb[(size_t)row * ldc + col] = f2bf(v);
          else if (C2 && col >= csplit)   C2[(size_t)row * ldc2 + (col - csplit)] = v;
          else                            C[(size_t)row * ldc + col] = v;
        }
      }
    }
  }
}

// ---------------------------------------------------------------------------
// transpose-convert: in fp32 [K][N] (row stride N) -> out bf16 [Nout][ldo]
__global__ __launch_bounds__(256) void k_wt(const float* __restrict__ in, int K, int N,
                                            u16* __restrict__ out, int ldo, int Nout) {
  __shared__ float s[32][33];
  int k0 = blockIdx.x * 32, n0 = blockIdx.y * 32;
  int tx = threadIdx.x & 31, ty = threadIdx.x >> 5;
#pragma unroll
  for (int i = 0; i < 4; ++i) {
    int k = k0 + ty + i * 8, n = n0 + tx;
    s[ty + i * 8][tx] = (n < N) ? in[(size_t)k * N + n] : 0.f;
  }
  __syncthreads();
#pragma unroll
  for (int i = 0; i < 4; ++i) {
    int n = n0 + ty + i * 8;
    if (n < Nout) out[(size_t)n * ldo + k0 + tx] = f2bf(s[tx][ty + i * 8]);
  }
}

// hbias[12672] = [W_b | bih+bhh | fcn_b | 0-pad]
__global__ __launch_bounds__(256) void k_hbias(const float* __restrict__ W_b,
                                               const float* __restrict__ bih,
                                               const float* __restrict__ bhh,
                                               const float* __restrict__ fcn_b,
                                               float* __restrict__ hbias) {
  int i = blockIdx.x * 256 + threadIdx.x;
  if (i >= HCAT_) return;
  float v;
  if (i < 512)        v = W_b[i];
  else if (i < 2560)  v = bih[i - 512] + bhh[i - 512];
  else if (i < 12560) v = fcn_b[i - 2560];
  else                v = 0.f;
  hbias[i] = v;
}

// emb_all_bf[t*128 + b][k] = bf16(emb[captions[b][t]][k])  for all 20 steps
__global__ __launch_bounds__(256) void k_embed_all(const float* __restrict__ emb,
                                                   const int* __restrict__ captions,
                                                   u16* __restrict__ emb_all_bf) {
  int r = blockIdx.y;               // r = t*128 + b
  int t = r >> 7, b = r & 127;
  int k = blockIdx.x * 256 + threadIdx.x;
  int tok = captions[b * 21 + t];
  emb_all_bf[(size_t)r * EMB_ + k] = f2bf(emb[(size_t)tok * EMB_ + k]);
}

// fused: features -> bf16 copy + per-(b,e) mean over n -> bf16.
__global__ __launch_bounds__(256) void k_cvtmean(const float* __restrict__ f,
                                                 u16* __restrict__ feat_bf,
                                                 u16* __restrict__ mean_bf) {
  int b = blockIdx.y;
  int e = (blockIdx.x * 256 + threadIdx.x) * 4;
  const float* p = f + (size_t)b * N_ * ENC_ + e;
  u16* q = feat_bf + (size_t)b * N_ * ENC_ + e;
  float s0 = 0.f, s1 = 0.f, s2 = 0.f, s3 = 0.f;
#pragma unroll 2
  for (int n = 0; n < N_; ++n) {
    float4 v = *(const float4*)(p + (size_t)n * ENC_);
    s0 += v.x; s1 += v.y; s2 += v.z; s3 += v.w;
    u16x4 o; o.x = f2bf(v.x); o.y = f2bf(v.y); o.z = f2bf(v.z); o.w = f2bf(v.w);
    *(u16x4*)(q + (size_t)n * ENC_) = o;
  }
  const float inv = 1.0f / (float)N_;
  u16x4 m; m.x = f2bf(s0 * inv); m.y = f2bf(s1 * inv);
  m.z = f2bf(s2 * inv); m.w = f2bf(s3 * inv);
  *(u16x4*)(mean_bf + b * ENC_ + e) = m;
}

// scores[b,n] = sum_a tanh(u_hs[b,n,a] + w_ah[b,a]) * A_w[a] + A_b ; 1 wave/(b,n)
__global__ __launch_bounds__(256) void k_scores(const u16* __restrict__ u_hs,
                                                const float* __restrict__ w_ah, int ldw,
                                                const float* __restrict__ A_w,
                                                const float* __restrict__ A_b,
                                                float* __restrict__ scores) {
  int wave = threadIdx.x >> 6;
  int lane = threadIdx.x & 63;
  int bn = blockIdx.x * 4 + wave;
  int b = bn / N_;
  int a0 = lane * 8;
  const u16* up = u_hs + (size_t)bn * ATT_ + a0;
  const float* wp = w_ah + (size_t)b * ldw + a0;
  float s = 0.f;
#pragma unroll
  for (int j = 0; j < 2; ++j) {
    u16x4 uv = *(const u16x4*)(up + j * 4);
    float4 wv = *(const float4*)(wp + j * 4);
    float4 aw = *(const float4*)(A_w + a0 + j * 4);
    s += fast_tanh(bf2f(uv.x) + wv.x) * aw.x;
    s += fast_tanh(bf2f(uv.y) + wv.y) * aw.y;
    s += fast_tanh(bf2f(uv.z) + wv.z) * aw.z;
    s += fast_tanh(bf2f(uv.w) + wv.w) * aw.w;
  }
#pragma unroll
  for (int off = 32; off; off >>= 1) s += __shfl_down(s, off);
  if (lane == 0) scores[bn] = s + A_b[0];
}

// fused per-b: softmax + alphas out + context -> ctx_bf.
// 512 threads (8 waves -> 16 waves/CU at 2 blocks/CU: 4x occupancy of the
// old 256-thr version; the 196-iter n-loop is latency-bound and needs TLP).
// grid (2, B): blockIdx.x halves the e-range; softmax duplicated.
__global__ __launch_bounds__(512) void k_ctx(const float* __restrict__ scores,
                                             const u16* __restrict__ feat_bf,
                                             float* __restrict__ alphas, int t,
                                             u16* __restrict__ ctx_bf) {
  int b = blockIdx.y, tid = threadIdx.x;
  int w = tid >> 6, lane = tid & 63;

  __shared__ float al[N_];
  __shared__ float wm[8], ws[8];
  __shared__ float bmax, bsum;
  float v = (tid < N_) ? scores[b * N_ + tid] : -1e30f;
  float m = v;
#pragma unroll
  for (int off = 32; off; off >>= 1) m = fmaxf(m, __shfl_down(m, off));
  if (lane == 0) wm[w] = m;
  __syncthreads();
  if (tid == 0) {
    float bm0 = wm[0];
#pragma unroll
    for (int i = 1; i < 8; ++i) bm0 = fmaxf(bm0, wm[i]);
    bmax = bm0;
  }
  __syncthreads();
  float e = (tid < N_) ? __expf(v - bmax) : 0.f;
  float s = e;
#pragma unroll
  for (int off = 32; off; off >>= 1) s += __shfl_down(s, off);
  if (lane == 0) ws[w] = s;
  __syncthreads();
  if (tid == 0) {
    float bs0 = 0.f;
#pragma unroll
    for (int i = 0; i < 8; ++i) bs0 += ws[i];
    bsum = bs0;
  }
  __syncthreads();
  float a = e / bsum;
  if (tid < N_) {
    al[tid] = a;
    if (blockIdx.x == 0) alphas[((size_t)b * TS_ + t) * N_ + tid] = a;
  }
  __syncthreads();

  int e0 = blockIdx.x * 1024 + tid * 2;
  const u16* fp = feat_bf + (size_t)b * N_ * ENC_ + e0;
  float s0 = 0, s1 = 0;
#pragma unroll 8
  for (int n = 0; n < N_; ++n) {
    u16x2 vv = *(const u16x2*)(fp + (size_t)n * ENC_);
    float av = al[n];
    s0 += av * bf2f(vv.x); s1 += av * bf2f(vv.y);
  }
  u16x2 o; o.x = f2bf(s0); o.y = f2bf(s1);
  *(u16x2*)(ctx_bf + (size_t)b * ENC_ + e0) = o;
}

// LSTM cell. gates = embgates[t] + hg + sum_z gatesP[z]  (split-K partials,
// replaces atomics AND the old gate-init pass), then activations.
// c (fp32) updated, h -> h_bf (bf16).
__global__ __launch_bounds__(256) void k_lstm(const float* __restrict__ gatesP,
                                              const float* __restrict__ embg_t,
                                              const float* __restrict__ houtt,
                                              float* __restrict__ c,
                                              u16* __restrict__ h_bf) {
  int b = blockIdx.y;
  int j = blockIdx.x * 256 + threadIdx.x;
  float g4[4];
#pragma unroll
  for (int gi = 0; gi < 4; ++gi) {
    int col = gi * 512 + j;
    float s = embg_t[(size_t)b * 2048 + col] + houtt[(size_t)b * HOUT_ + 512 + col];
#pragma unroll
    for (int z = 0; z < KSPLIT_; ++z)
      s += gatesP[(size_t)z * B_ * 2048 + (size_t)b * 2048 + col];
    g4[gi] = s;
  }
  float ig = fast_sigmoid(g4[0]);
  float fg = fast_sigmoid(g4[1]);
  float gg = fast_tanh(g4[2]);
  float og = fast_sigmoid(g4[3]);
  float cn = fg * c[b * DEC_ + j] + ig * gg;
  c[b * DEC_ + j] = cn;
  h_bf[(size_t)b * DEC_ + j] = f2bf(og * fast_tanh(cn));
}

// ---------------------------------------------------------------------------
extern "C" void kernel_launch(void* const* d_in, const int* in_sizes, int n_in,
                              void* d_out, int out_size, void* d_ws, size_t ws_size,
                              hipStream_t stream) {
  (void)in_sizes; (void)n_in; (void)out_size; (void)ws_size;

  const float* features = (const float*)d_in[0];
  const int*   captions = (const int*)d_in[1];
  const float* emb      = (const float*)d_in[2];
  const float* U_w      = (const float*)d_in[3];
  const float* U_b      = (const float*)d_in[4];
  const float* W_w      = (const float*)d_in[5];
  const float* W_b      = (const float*)d_in[6];
  const float* A_w      = (const float*)d_in[7];
  const float* A_b      = (const float*)d_in[8];
  const float* ih_w     = (const float*)d_in[9];
  const float* ih_b     = (const float*)d_in[10];
  const float* ic_w     = (const float*)d_in[11];
  const float* ic_b     = (const float*)d_in[12];
  const float* Wih      = (const float*)d_in[13];
  const float* Whh      = (const float*)d_in[14];
  const float* bih      = (const float*)d_in[15];
  const float* bhh      = (const float*)d_in[16];
  const float* fcn_w    = (const float*)d_in[17];
  const float* fcn_b    = (const float*)d_in[18];

  float* preds  = (float*)d_out;                          // (B, 20, V)
  float* alphas = (float*)d_out + (size_t)B_ * TS_ * V_;  // (B, 20, N)

  // workspace layout (float units; all offsets %4==0 -> 16B aligned)
  float* p = (float*)d_ws;
  u16*   u_hs      = (u16*)p;    p += (size_t)B_ * N_ * ATT_ / 2;    // bf16 (B*N, 512)
  u16*   feat_bf   = (u16*)p;    p += (size_t)B_ * N_ * ENC_ / 2;    // bf16 (B*N, 2048)
  u16*   hcatT     = (u16*)p;    p += (size_t)HCAT_ * DEC_ / 2;      // [12672][512]
  u16*   U_wT      = (u16*)p;    p += (size_t)ATT_ * ENC_ / 2;       // [512][2048]
  u16*   ih_wT     = (u16*)p;    p += (size_t)DEC_ * ENC_ / 2;
  u16*   ic_wT     = (u16*)p;    p += (size_t)DEC_ * ENC_ / 2;
  u16*   WihEmbT   = (u16*)p;    p += (size_t)2048 * EMB_ / 2;       // [2048][512]
  u16*   WihCtxT   = (u16*)p;    p += (size_t)2048 * ENC_ / 2;       // [2048][2048]
  u16*   mean_bf   = (u16*)p;    p += (size_t)B_ * ENC_ / 2;
  u16*   emb_all   = (u16*)p;    p += (size_t)TS_ * B_ * EMB_ / 2;   // [2560][512]
  u16*   h_bf      = (u16*)p;    p += (size_t)B_ * DEC_ / 2;         // [128][512]
  u16*   ctx_bf    = (u16*)p;    p += (size_t)B_ * ENC_ / 2;         // [128][2048]
  float* embgates  = p;          p += (size_t)TS_ * B_ * 2048;       // fp32 [2560][2048]
  float* houtt     = p;          p += (size_t)B_ * HOUT_;            // fp32 [128][2560]
  float* cbuf      = p;          p += (size_t)B_ * DEC_;
  float* scores    = p;          p += (size_t)B_ * N_;
  float* gatesP    = p;          p += (size_t)KSPLIT_ * B_ * 2048;   // split-K partials
  float* hbias     = p;          p += HCAT_;

  // ---- one-time ----
  k_cvtmean<<<dim3(ENC_ / 1024, B_), 256, 0, stream>>>(features, feat_bf, mean_bf);
  k_wt<<<dim3(ENC_ / 32, ATT_ / 32), 256, 0, stream>>>(U_w, ENC_, ATT_, U_wT, ENC_, ATT_);
  k_wt<<<dim3(ENC_ / 32, DEC_ / 32), 256, 0, stream>>>(ih_w, ENC_, DEC_, ih_wT, ENC_, DEC_);
  k_wt<<<dim3(ENC_ / 32, DEC_ / 32), 256, 0, stream>>>(ic_w, ENC_, DEC_, ic_wT, ENC_, DEC_);
  // hcatT = [W_w | Whh | fcn_w]^T, each row K=512
  k_wt<<<dim3(DEC_ / 32, ATT_ / 32), 256, 0, stream>>>(W_w, DEC_, ATT_, hcatT, DEC_, ATT_);
  k_wt<<<dim3(DEC_ / 32, 2048 / 32), 256, 0, stream>>>(Whh, DEC_, 2048, hcatT + (size_t)512 * DEC_, DEC_, 2048);
  k_wt<<<dim3(DEC_ / 32, 10112 / 32), 256, 0, stream>>>(fcn_w, DEC_, V_, hcatT + (size_t)2560 * DEC_, DEC_, 10112);
  // Wih split: rows [0:512) emb part, rows [512:2560) ctx part
  k_wt<<<dim3(EMB_ / 32, 2048 / 32), 256, 0, stream>>>(Wih, EMB_, 2048, WihEmbT, EMB_, 2048);
  k_wt<<<dim3(ENC_ / 32, 2048 / 32), 256, 0, stream>>>(Wih + (size_t)EMB_ * 2048, ENC_, 2048, WihCtxT, ENC_, 2048);
  k_hbias<<<(HCAT_ + 255) / 256, 256, 0, stream>>>(W_b, bih, bhh, fcn_b, hbias);
  k_embed_all<<<dim3(EMB_ / 256, TS_ * B_), 256, 0, stream>>>(emb, captions, emb_all);

  // h0 (bf16 into h_bf), c0 (fp32)
  k_mfma<<<dim3(4, 1, 1), 256, 0, stream>>>(mean_bf, ENC_, ih_wT, ENC_, ih_b,
                                            nullptr, h_bf, DEC_, DEC_, nullptr, 0, 0, ENC_, 0);
  k_mfma<<<dim3(4, 1, 1), 256, 0, stream>>>(mean_bf, ENC_, ic_wT, ENC_, ic_b,
                                            cbuf, nullptr, DEC_, DEC_, nullptr, 0, 0, ENC_, 0);
  // u_hs = bf16(features @ U_w + U_b)   (25088 x 512 x 2048)
  k_mfma<<<dim3(ATT_ / 128, (B_ * N_) / 128, 1), 256, 0, stream>>>(
      feat_bf, ENC_, U_wT, ENC_, U_b, nullptr, u_hs, ATT_, ATT_, nullptr, 0, 0, ENC_, 0);
  // embgates[t*128+b] = emb_t @ Wih_emb   (2560 x 2048 x 512), bias folded into hbias
  k_mfma<<<dim3(2048 / 128, TS_, 1), 256, 0, stream>>>(
      emb_all, EMB_, WihEmbT, EMB_, nullptr, embgates, nullptr, 2048, 2048, nullptr, 0, 0, EMB_, 0);

  // ---- decode steps (5 launches/step) ----
  // preds[t] uses the POST-LSTM h of step t: the fused h-GEMM at iteration t
  // (consuming h = post-LSTM h of step t-1) emits preds[t-1]; t=0 runs the
  // [w_ah|hg]-only slice; preds[19] is a final GEMM after the loop.
  for (int t = 0; t < TS_; ++t) {
    if (t == 0) {
      k_mfma<<<dim3(HOUT_ / 128, 1, 1), 256, 0, stream>>>(
          h_bf, DEC_, hcatT, DEC_, hbias, houtt, nullptr, HOUT_, HOUT_,
          nullptr, 0, 0, DEC_, 0);
    } else {
      k_mfma<<<dim3(HCAT_ / 128, 1, 1), 256, 0, stream>>>(
          h_bf, DEC_, hcatT, DEC_, hbias, houtt, nullptr, HOUT_, 12560,
          preds + (size_t)(t - 1) * V_, HOUT_, TS_ * V_, DEC_, 0);
    }

    k_scores<<<(B_ * N_) / 4, 256, 0, stream>>>(u_hs, houtt, HOUT_, A_w, A_b, scores);

    // softmax + alphas + context
    k_ctx<<<dim3(2, B_), 512, 0, stream>>>(scores, feat_bf, alphas, t, ctx_bf);

    // gatesP[z] = ctx @ Wih_ctx (K-chunk z)   (128 x 2048 x 2048, split-K=8)
    k_mfma<<<dim3(2048 / 128, 1, KSPLIT_), 256, 0, stream>>>(
        ctx_bf, ENC_, WihCtxT, ENC_, nullptr, gatesP, nullptr, 2048, 2048, nullptr, 0, 0, ENC_, 2);

    // gates = embgates[t] + hg + sum_z gatesP[z]; LSTM cell
    k_lstm<<<dim3(DEC_ / 256, B_), 256, 0, stream>>>(gatesP, embgates + (size_t)t * B_ * 2048,
                                                     houtt, cbuf, h_bf);
  }

  // preds[:, 19, :] = h @ fcn_w + fcn_b   (final h after step 19's LSTM)
  k_mfma<<<dim3(10112 / 128, 1, 1), 256, 0, stream>>>(
      h_bf, DEC_, hcatT + (size_t)2560 * DEC_, DEC_, hbias + 2560,
      preds + (size_t)(TS_ - 1) * V_, nullptr, TS_ * V_, V_, nullptr, 0, 0, DEC_, 0);
}

// Round 7
// 1874.873 us; speedup vs baseline: 1.0526x; 1.0526x over previous
//
#include <hip/hip_runtime.h>
#include <cmath>

#define B_   128
#define N_   196
#define ENC_ 2048
#define DEC_ 512
#define ATT_ 512
#define EMB_ 512
#define V_   10000
#define TS_  20     // T-1 decode steps
#define HCAT_ 12672 // 512 (W_w) + 2048 (Whh) + 10112 (fcn padded)
#define HOUT_ 2560  // [w_ah(512) | hg(2048)]
#define KSPLIT_ 8   // split-K for gates GEMM

typedef unsigned short u16;
typedef short s16x8 __attribute__((ext_vector_type(8)));   // 8 bf16 = 4 VGPRs (MFMA A/B frag)
typedef float f32x4 __attribute__((ext_vector_type(4)));   // MFMA C/D frag
typedef unsigned short u16x4 __attribute__((ext_vector_type(4)));
typedef unsigned short u16x2 __attribute__((ext_vector_type(2)));

// fast tanh: (e^{2x}-1)/(e^{2x}+1), clamp |x|<=8. ~6 VALU vs ~25 libm; err ~1e-7.
__device__ __forceinline__ float fast_tanh(float x) {
  float cx = fminf(fmaxf(x, -8.f), 8.f);
  float e = __expf(2.f * cx);
  return (e - 1.f) * __builtin_amdgcn_rcpf(e + 1.f);
}
__device__ __forceinline__ float fast_sigmoid(float x) {
  float cx = fminf(fmaxf(x, -30.f), 30.f);
  return __builtin_amdgcn_rcpf(1.f + __expf(-cx));
}

__device__ __forceinline__ u16 f2bf(float x) {  // round-to-nearest-even
  union { float f; unsigned u; } v; v.f = x;
  unsigned r = v.u + 0x7fff + ((v.u >> 16) & 1);
  return (u16)(r >> 16);
}
__device__ __forceinline__ float bf2f(u16 h) {
  union { float f; unsigned u; } v; v.u = ((unsigned)h) << 16; return v.f;
}

typedef const __attribute__((address_space(1))) void gas_t;
typedef __attribute__((address_space(3))) void las_t;
__device__ __forceinline__ void gld_lds16(const void* g, void* l) {
  __builtin_amdgcn_global_load_lds((gas_t*)g, (las_t*)l, 16, 0, 0);
}

// ---------------------------------------------------------------------------
// bf16 MFMA GEMM: C(M,N) = A(M,K) @ Bt(N,K)^T [+ bias]
// Tile 128x128, BK=64, 256 threads (4 waves, 2x2), 16x16x32 MFMA,
// double-buffered LDS (64 KB).
// T2 XOR-SWIZZLE (m173/m201 pattern, rule #21 both-sides): LDS stays linear
// (global_load_lds writes base+lane*16); each lane's GLOBAL source chunk is
// pre-swizzled by (tid&7)^((tid>>3)&7), so LDS[row][c] = global[row][c^(row&7)];
// the ds_read index applies the same XOR. Kills the 128B-row-stride 16/32-way
// bank conflict (1.9e7 conflicts measured in round 6's linear layout).
// Epilogue routing: mode 1 -> atomicAdd C; mode 2 -> split-K partials
// (C += z*128*ldc, plain stores); Cb -> bf16 store; C2 (cols>=csplit) ->
// fp32 store with ldc2 (dual-output for the fused h-GEMM); else fp32 C.
__global__ __launch_bounds__(256, 2) void k_mfma(
    const u16* __restrict__ A, int lda,
    const u16* __restrict__ Bt, int ldb,
    const float* __restrict__ bias,
    float* __restrict__ C, u16* __restrict__ Cb, int ldc, int Nbound,
    float* __restrict__ C2, int csplit, int ldc2,
    int K, int mode) {
  __shared__ __align__(16) u16 As[2][128 * 64];
  __shared__ __align__(16) u16 Bs[2][128 * 64];

  const int tid = threadIdx.x;
  const int bm = blockIdx.y * 128;
  const int bn = blockIdx.x * 128;
  const int kchunk = K / gridDim.z;
  const int k0 = blockIdx.z * kchunk;
  const int kend = k0 + kchunk;
  if (mode == 2) C += (size_t)blockIdx.z * 128 * ldc;   // split-K partial buffer

  // staging: thread -> one 16B chunk; 4 passes/matrix (32 rows per pass).
  // Linear LDS dest chunk = tid&7; swizzled global source chunk = ^(row&7).
  const int r0 = tid >> 3;                    // row-within-pass 0..31
  const int kb = ((tid & 7) ^ (r0 & 7)) * 8;  // swizzled k offset (row&7 == r0&7 for all passes)
  const u16* ga = A + (size_t)(bm + r0) * lda + kb;
  const u16* gb = Bt + (size_t)(bn + r0) * ldb + kb;

  const int w = tid >> 6;
  const int lane = tid & 63;
  const int wm = (w & 1) * 64;
  const int wn = (w >> 1) * 64;
  const int r16 = lane & 15;
  const int kq = lane >> 4;

  f32x4 acc[4][4] = {};

  auto STAGE = [&](int buf, int k) {
#pragma unroll
    for (int j = 0; j < 4; ++j) {
      gld_lds16(ga + (size_t)(j * 32) * lda + k, &As[buf][j * 2048 + tid * 8]);
      gld_lds16(gb + (size_t)(j * 32) * ldb + k, &Bs[buf][j * 2048 + tid * 8]);
    }
  };

  STAGE(0, k0);
  __syncthreads();               // drain prologue loads; buf0 ready
  int cur = 0;
  for (int k = k0; k < kend; k += 64) {
    if (k + 64 < kend) STAGE(cur ^ 1, k + 64);   // prefetch next tile
    s16x8 af[2][4], bfr[2][4];
    const int rx = r16 & 7;                       // row&7 for swizzled read
#pragma unroll
    for (int s = 0; s < 2; ++s)
#pragma unroll
      for (int i = 0; i < 4; ++i) {
        int ca = ((s * 4 + kq) ^ rx) << 3;        // swizzled chunk -> u16 offset
        af[s][i]  = *(const s16x8*)&As[cur][(wm + i * 16 + r16) * 64 + ca];
        bfr[s][i] = *(const s16x8*)&Bs[cur][(wn + i * 16 + r16) * 64 + ca];
      }
#pragma unroll
    for (int s = 0; s < 2; ++s)
#pragma unroll
      for (int mi = 0; mi < 4; ++mi)
#pragma unroll
        for (int ni = 0; ni < 4; ++ni)
          acc[mi][ni] = __builtin_amdgcn_mfma_f32_16x16x32_bf16(af[s][mi], bfr[s][ni], acc[mi][ni], 0, 0, 0);
    __syncthreads();             // publish prefetched buf + protect cur
    cur ^= 1;
  }

  // C/D layout: col = lane&15, row = quad*4 + reg (m89-verified)
#pragma unroll
  for (int ni = 0; ni < 4; ++ni) {
    int col = bn + wn + ni * 16 + r16;
    if (col < Nbound) {
      float bv = bias ? bias[col] : 0.f;
#pragma unroll
      for (int mi = 0; mi < 4; ++mi) {
#pragma unroll
        for (int r = 0; r < 4; ++r) {
          int row = bm + wm + mi * 16 + kq * 4 + r;
          float v = acc[mi][ni][r] + bv;
          if (mode == 1)                  atomicAdd(&C[(size_t)row * ldc + col], v);
          else if (Cb)                    Cb[(size_t)row * ldc + col] = f2bf(v);
          else if (C2 && col >= csplit)   C2[(size_t)row * ldc2 + (col - csplit)] = v;
          else                            C[(size_t)row * ldc + col] = v;
        }
      }
    }
  }
}

// ---------------------------------------------------------------------------
// transpose-convert: in fp32 [K][N] (row stride N) -> out bf16 [Nout][ldo]
__global__ __launch_bounds__(256) void k_wt(const float* __restrict__ in, int K, int N,
                                            u16* __restrict__ out, int ldo, int Nout) {
  __shared__ float s[32][33];
  int k0 = blockIdx.x * 32, n0 = blockIdx.y * 32;
  int tx = threadIdx.x & 31, ty = threadIdx.x >> 5;
#pragma unroll
  for (int i = 0; i < 4; ++i) {
    int k = k0 + ty + i * 8, n = n0 + tx;
    s[ty + i * 8][tx] = (n < N) ? in[(size_t)k * N + n] : 0.f;
  }
  __syncthreads();
#pragma unroll
  for (int i = 0; i < 4; ++i) {
    int n = n0 + ty + i * 8;
    if (n < Nout) out[(size_t)n * ldo + k0 + tx] = f2bf(s[tx][ty + i * 8]);
  }
}

// hbias[12672] = [W_b | bih+bhh | fcn_b | 0-pad]
__global__ __launch_bounds__(256) void k_hbias(const float* __restrict__ W_b,
                                               const float* __restrict__ bih,
                                               const float* __restrict__ bhh,
                                               const float* __restrict__ fcn_b,
                                               float* __restrict__ hbias) {
  int i = blockIdx.x * 256 + threadIdx.x;
  if (i >= HCAT_) return;
  float v;
  if (i < 512)        v = W_b[i];
  else if (i < 2560)  v = bih[i - 512] + bhh[i - 512];
  else if (i < 12560) v = fcn_b[i - 2560];
  else                v = 0.f;
  hbias[i] = v;
}

// emb_all_bf[t*128 + b][k] = bf16(emb[captions[b][t]][k])  for all 20 steps
__global__ __launch_bounds__(256) void k_embed_all(const float* __restrict__ emb,
                                                   const int* __restrict__ captions,
                                                   u16* __restrict__ emb_all_bf) {
  int r = blockIdx.y;               // r = t*128 + b
  int t = r >> 7, b = r & 127;
  int k = blockIdx.x * 256 + threadIdx.x;
  int tok = captions[b * 21 + t];
  emb_all_bf[(size_t)r * EMB_ + k] = f2bf(emb[(size_t)tok * EMB_ + k]);
}

// fused: features -> bf16 copy + per-(b,e) mean over n -> bf16.
__global__ __launch_bounds__(256) void k_cvtmean(const float* __restrict__ f,
                                                 u16* __restrict__ feat_bf,
                                                 u16* __restrict__ mean_bf) {
  int b = blockIdx.y;
  int e = (blockIdx.x * 256 + threadIdx.x) * 4;
  const float* p = f + (size_t)b * N_ * ENC_ + e;
  u16* q = feat_bf + (size_t)b * N_ * ENC_ + e;
  float s0 = 0.f, s1 = 0.f, s2 = 0.f, s3 = 0.f;
#pragma unroll 2
  for (int n = 0; n < N_; ++n) {
    float4 v = *(const float4*)(p + (size_t)n * ENC_);
    s0 += v.x; s1 += v.y; s2 += v.z; s3 += v.w;
    u16x4 o; o.x = f2bf(v.x); o.y = f2bf(v.y); o.z = f2bf(v.z); o.w = f2bf(v.w);
    *(u16x4*)(q + (size_t)n * ENC_) = o;
  }
  const float inv = 1.0f / (float)N_;
  u16x4 m; m.x = f2bf(s0 * inv); m.y = f2bf(s1 * inv);
  m.z = f2bf(s2 * inv); m.w = f2bf(s3 * inv);
  *(u16x4*)(mean_bf + b * ENC_ + e) = m;
}

// scores[b,n] = sum_a tanh(u_hs[b,n,a] + w_ah[b,a]) * A_w[a] + A_b ; 1 wave/(b,n)
__global__ __launch_bounds__(256) void k_scores(const u16* __restrict__ u_hs,
                                                const float* __restrict__ w_ah, int ldw,
                                                const float* __restrict__ A_w,
                                                const float* __restrict__ A_b,
                                                float* __restrict__ scores) {
  int wave = threadIdx.x >> 6;
  int lane = threadIdx.x & 63;
  int bn = blockIdx.x * 4 + wave;
  int b = bn / N_;
  int a0 = lane * 8;
  const u16* up = u_hs + (size_t)bn * ATT_ + a0;
  const float* wp = w_ah + (size_t)b * ldw + a0;
  float s = 0.f;
#pragma unroll
  for (int j = 0; j < 2; ++j) {
    u16x4 uv = *(const u16x4*)(up + j * 4);
    float4 wv = *(const float4*)(wp + j * 4);
    float4 aw = *(const float4*)(A_w + a0 + j * 4);
    s += fast_tanh(bf2f(uv.x) + wv.x) * aw.x;
    s += fast_tanh(bf2f(uv.y) + wv.y) * aw.y;
    s += fast_tanh(bf2f(uv.z) + wv.z) * aw.z;
    s += fast_tanh(bf2f(uv.w) + wv.w) * aw.w;
  }
#pragma unroll
  for (int off = 32; off; off >>= 1) s += __shfl_down(s, off);
  if (lane == 0) scores[bn] = s + A_b[0];
}

// fused per-b: softmax + alphas out + context -> ctx_bf.
// 512 threads (8 waves); grid (2, B): blockIdx.x halves the e-range.
__global__ __launch_bounds__(512) void k_ctx(const float* __restrict__ scores,
                                             const u16* __restrict__ feat_bf,
                                             float* __restrict__ alphas, int t,
                                             u16* __restrict__ ctx_bf) {
  int b = blockIdx.y, tid = threadIdx.x;
  int w = tid >> 6, lane = tid & 63;

  __shared__ float al[N_];
  __shared__ float wm[8], ws[8];
  __shared__ float bmax, bsum;
  float v = (tid < N_) ? scores[b * N_ + tid] : -1e30f;
  float m = v;
#pragma unroll
  for (int off = 32; off; off >>= 1) m = fmaxf(m, __shfl_down(m, off));
  if (lane == 0) wm[w] = m;
  __syncthreads();
  if (tid == 0) {
    float bm0 = wm[0];
#pragma unroll
    for (int i = 1; i < 8; ++i) bm0 = fmaxf(bm0, wm[i]);
    bmax = bm0;
  }
  __syncthreads();
  float e = (tid < N_) ? __expf(v - bmax) : 0.f;
  float s = e;
#pragma unroll
  for (int off = 32; off; off >>= 1) s += __shfl_down(s, off);
  if (lane == 0) ws[w] = s;
  __syncthreads();
  if (tid == 0) {
    float bs0 = 0.f;
#pragma unroll
    for (int i = 0; i < 8; ++i) bs0 += ws[i];
    bsum = bs0;
  }
  __syncthreads();
  float a = e / bsum;
  if (tid < N_) {
    al[tid] = a;
    if (blockIdx.x == 0) alphas[((size_t)b * TS_ + t) * N_ + tid] = a;
  }
  __syncthreads();

  int e0 = blockIdx.x * 1024 + tid * 2;
  const u16* fp = feat_bf + (size_t)b * N_ * ENC_ + e0;
  float s0 = 0, s1 = 0;
#pragma unroll 8
  for (int n = 0; n < N_; ++n) {
    u16x2 vv = *(const u16x2*)(fp + (size_t)n * ENC_);
    float av = al[n];
    s0 += av * bf2f(vv.x); s1 += av * bf2f(vv.y);
  }
  u16x2 o; o.x = f2bf(s0); o.y = f2bf(s1);
  *(u16x2*)(ctx_bf + (size_t)b * ENC_ + e0) = o;
}

// LSTM cell. gates = embgates[t] + hg + sum_z gatesP[z]  (split-K partials),
// then activations. c (fp32) updated, h -> h_bf (bf16).
__global__ __launch_bounds__(256) void k_lstm(const float* __restrict__ gatesP,
                                              const float* __restrict__ embg_t,
                                              const float* __restrict__ houtt,
                                              float* __restrict__ c,
                                              u16* __restrict__ h_bf) {
  int b = blockIdx.y;
  int j = blockIdx.x * 256 + threadIdx.x;
  float g4[4];
#pragma unroll
  for (int gi = 0; gi < 4; ++gi) {
    int col = gi * 512 + j;
    float s = embg_t[(size_t)b * 2048 + col] + houtt[(size_t)b * HOUT_ + 512 + col];
#pragma unroll
    for (int z = 0; z < KSPLIT_; ++z)
      s += gatesP[(size_t)z * B_ * 2048 + (size_t)b * 2048 + col];
    g4[gi] = s;
  }
  float ig = fast_sigmoid(g4[0]);
  float fg = fast_sigmoid(g4[1]);
  float gg = fast_tanh(g4[2]);
  float og = fast_sigmoid(g4[3]);
  float cn = fg * c[b * DEC_ + j] + ig * gg;
  c[b * DEC_ + j] = cn;
  h_bf[(size_t)b * DEC_ + j] = f2bf(og * fast_tanh(cn));
}

// ---------------------------------------------------------------------------
extern "C" void kernel_launch(void* const* d_in, const int* in_sizes, int n_in,
                              void* d_out, int out_size, void* d_ws, size_t ws_size,
                              hipStream_t stream) {
  (void)in_sizes; (void)n_in; (void)out_size; (void)ws_size;

  const float* features = (const float*)d_in[0];
  const int*   captions = (const int*)d_in[1];
  const float* emb      = (const float*)d_in[2];
  const float* U_w      = (const float*)d_in[3];
  const float* U_b      = (const float*)d_in[4];
  const float* W_w      = (const float*)d_in[5];
  const float* W_b      = (const float*)d_in[6];
  const float* A_w      = (const float*)d_in[7];
  const float* A_b      = (const float*)d_in[8];
  const float* ih_w     = (const float*)d_in[9];
  const float* ih_b     = (const float*)d_in[10];
  const float* ic_w     = (const float*)d_in[11];
  const float* ic_b     = (const float*)d_in[12];
  const float* Wih      = (const float*)d_in[13];
  const float* Whh      = (const float*)d_in[14];
  const float* bih      = (const float*)d_in[15];
  const float* bhh      = (const float*)d_in[16];
  const float* fcn_w    = (const float*)d_in[17];
  const float* fcn_b    = (const float*)d_in[18];

  float* preds  = (float*)d_out;                          // (B, 20, V)
  float* alphas = (float*)d_out + (size_t)B_ * TS_ * V_;  // (B, 20, N)

  // workspace layout (float units; all offsets %4==0 -> 16B aligned)
  float* p = (float*)d_ws;
  u16*   u_hs      = (u16*)p;    p += (size_t)B_ * N_ * ATT_ / 2;    // bf16 (B*N, 512)
  u16*   feat_bf   = (u16*)p;    p += (size_t)B_ * N_ * ENC_ / 2;    // bf16 (B*N, 2048)
  u16*   hcatT     = (u16*)p;    p += (size_t)HCAT_ * DEC_ / 2;      // [12672][512]
  u16*   U_wT      = (u16*)p;    p += (size_t)ATT_ * ENC_ / 2;       // [512][2048]
  u16*   ih_wT     = (u16*)p;    p += (size_t)DEC_ * ENC_ / 2;
  u16*   ic_wT     = (u16*)p;    p += (size_t)DEC_ * ENC_ / 2;
  u16*   WihEmbT   = (u16*)p;    p += (size_t)2048 * EMB_ / 2;       // [2048][512]
  u16*   WihCtxT   = (u16*)p;    p += (size_t)2048 * ENC_ / 2;       // [2048][2048]
  u16*   mean_bf   = (u16*)p;    p += (size_t)B_ * ENC_ / 2;
  u16*   emb_all   = (u16*)p;    p += (size_t)TS_ * B_ * EMB_ / 2;   // [2560][512]
  u16*   h_bf      = (u16*)p;    p += (size_t)B_ * DEC_ / 2;         // [128][512]
  u16*   ctx_bf    = (u16*)p;    p += (size_t)B_ * ENC_ / 2;         // [128][2048]
  float* embgates  = p;          p += (size_t)TS_ * B_ * 2048;       // fp32 [2560][2048]
  float* houtt     = p;          p += (size_t)B_ * HOUT_;            // fp32 [128][2560]
  float* cbuf      = p;          p += (size_t)B_ * DEC_;
  float* scores    = p;          p += (size_t)B_ * N_;
  float* gatesP    = p;          p += (size_t)KSPLIT_ * B_ * 2048;   // split-K partials
  float* hbias     = p;          p += HCAT_;

  // ---- one-time ----
  k_cvtmean<<<dim3(ENC_ / 1024, B_), 256, 0, stream>>>(features, feat_bf, mean_bf);
  k_wt<<<dim3(ENC_ / 32, ATT_ / 32), 256, 0, stream>>>(U_w, ENC_, ATT_, U_wT, ENC_, ATT_);
  k_wt<<<dim3(ENC_ / 32, DEC_ / 32), 256, 0, stream>>>(ih_w, ENC_, DEC_, ih_wT, ENC_, DEC_);
  k_wt<<<dim3(ENC_ / 32, DEC_ / 32), 256, 0, stream>>>(ic_w, ENC_, DEC_, ic_wT, ENC_, DEC_);
  // hcatT = [W_w | Whh | fcn_w]^T, each row K=512
  k_wt<<<dim3(DEC_ / 32, ATT_ / 32), 256, 0, stream>>>(W_w, DEC_, ATT_, hcatT, DEC_, ATT_);
  k_wt<<<dim3(DEC_ / 32, 2048 / 32), 256, 0, stream>>>(Whh, DEC_, 2048, hcatT + (size_t)512 * DEC_, DEC_, 2048);
  k_wt<<<dim3(DEC_ / 32, 10112 / 32), 256, 0, stream>>>(fcn_w, DEC_, V_, hcatT + (size_t)2560 * DEC_, DEC_, 10112);
  // Wih split: rows [0:512) emb part, rows [512:2560) ctx part
  k_wt<<<dim3(EMB_ / 32, 2048 / 32), 256, 0, stream>>>(Wih, EMB_, 2048, WihEmbT, EMB_, 2048);
  k_wt<<<dim3(ENC_ / 32, 2048 / 32), 256, 0, stream>>>(Wih + (size_t)EMB_ * 2048, ENC_, 2048, WihCtxT, ENC_, 2048);
  k_hbias<<<(HCAT_ + 255) / 256, 256, 0, stream>>>(W_b, bih, bhh, fcn_b, hbias);
  k_embed_all<<<dim3(EMB_ / 256, TS_ * B_), 256, 0, stream>>>(emb, captions, emb_all);

  // h0 (bf16 into h_bf), c0 (fp32)
  k_mfma<<<dim3(4, 1, 1), 256, 0, stream>>>(mean_bf, ENC_, ih_wT, ENC_, ih_b,
                                            nullptr, h_bf, DEC_, DEC_, nullptr, 0, 0, ENC_, 0);
  k_mfma<<<dim3(4, 1, 1), 256, 0, stream>>>(mean_bf, ENC_, ic_wT, ENC_, ic_b,
                                            cbuf, nullptr, DEC_, DEC_, nullptr, 0, 0, ENC_, 0);
  // u_hs = bf16(features @ U_w + U_b)   (25088 x 512 x 2048)
  k_mfma<<<dim3(ATT_ / 128, (B_ * N_) / 128, 1), 256, 0, stream>>>(
      feat_bf, ENC_, U_wT, ENC_, U_b, nullptr, u_hs, ATT_, ATT_, nullptr, 0, 0, ENC_, 0);
  // embgates[t*128+b] = emb_t @ Wih_emb   (2560 x 2048 x 512), bias folded into hbias
  k_mfma<<<dim3(2048 / 128, TS_, 1), 256, 0, stream>>>(
      emb_all, EMB_, WihEmbT, EMB_, nullptr, embgates, nullptr, 2048, 2048, nullptr, 0, 0, EMB_, 0);

  // ---- decode steps (5 launches/step) ----
  // preds[t] uses the POST-LSTM h of step t: the fused h-GEMM at iteration t
  // (consuming h = post-LSTM h of step t-1) emits preds[t-1]; t=0 runs the
  // [w_ah|hg]-only slice; preds[19] is a final GEMM after the loop.
  for (int t = 0; t < TS_; ++t) {
    if (t == 0) {
      k_mfma<<<dim3(HOUT_ / 128, 1, 1), 256, 0, stream>>>(
          h_bf, DEC_, hcatT, DEC_, hbias, houtt, nullptr, HOUT_, HOUT_,
          nullptr, 0, 0, DEC_, 0);
    } else {
      k_mfma<<<dim3(HCAT_ / 128, 1, 1), 256, 0, stream>>>(
          h_bf, DEC_, hcatT, DEC_, hbias, houtt, nullptr, HOUT_, 12560,
          preds + (size_t)(t - 1) * V_, HOUT_, TS_ * V_, DEC_, 0);
    }

    k_scores<<<(B_ * N_) / 4, 256, 0, stream>>>(u_hs, houtt, HOUT_, A_w, A_b, scores);

    // softmax + alphas + context
    k_ctx<<<dim3(2, B_), 512, 0, stream>>>(scores, feat_bf, alphas, t, ctx_bf);

    // gatesP[z] = ctx @ Wih_ctx (K-chunk z)   (128 x 2048 x 2048, split-K=8)
    k_mfma<<<dim3(2048 / 128, 1, KSPLIT_), 256, 0, stream>>>(
        ctx_bf, ENC_, WihCtxT, ENC_, nullptr, gatesP, nullptr, 2048, 2048, nullptr, 0, 0, ENC_, 2);

    // gates = embgates[t] + hg + sum_z gatesP[z]; LSTM cell
    k_lstm<<<dim3(DEC_ / 256, B_), 256, 0, stream>>>(gatesP, embgates + (size_t)t * B_ * 2048,
                                                     houtt, cbuf, h_bf);
  }

  // preds[:, 19, :] = h @ fcn_w + fcn_b   (final h after step 19's LSTM)
  k_mfma<<<dim3(10112 / 128, 1, 1), 256, 0, stream>>>(
      h_bf, DEC_, hcatT + (size_t)2560 * DEC_, DEC_, hbias + 2560,
      preds + (size_t)(TS_ - 1) * V_, nullptr, TS_ * V_, V_, nullptr, 0, 0, DEC_, 0);
}